// Round 4
// baseline (213.608 us; speedup 1.0000x reference)
//
#include <hip/hip_runtime.h>
#include <hip/hip_bf16.h>
#include <cmath>

#define BATCH 4
#define SEQ 2048
#define DM 1024
#define NS 16
#define M_ROWS (BATCH * SEQ)

typedef short bf16x8 __attribute__((ext_vector_type(8)));
typedef short bf16x4 __attribute__((ext_vector_type(4)));
typedef float f32x4 __attribute__((ext_vector_type(4)));

// fp32 -> bf16 round-to-nearest-even
__device__ __forceinline__ short f2bf(float f) {
    union { float f; unsigned u; } a; a.f = f;
    unsigned u = a.u;
    return (short)((u + 0x7fffu + ((u >> 16) & 1u)) >> 16);
}
__device__ __forceinline__ float bf2f(unsigned short s) {
    union { unsigned u; float f; } a; a.u = ((unsigned)s) << 16;
    return a.f;
}

// ---------------------------------------------------------------------------
// Kernel 0: convert x, W1, W2, W3 fp32 -> bf16. Block-uniform segment select.
// Wcb = [W2(16 rows); W3(16 rows)], row-major, K contiguous.
// ---------------------------------------------------------------------------
__global__ void __launch_bounds__(256) convert_all(
    const float* __restrict__ x,  const float* __restrict__ W1,
    const float* __restrict__ W2, const float* __restrict__ W3,
    short* __restrict__ xb, short* __restrict__ W1b, short* __restrict__ Wcb)
{
    const int b = blockIdx.x;
    const int t = threadIdx.x;
    const float4* src; bf16x4* dst; int qbase;
    if (b < 2048)      { src = (const float4*)x;  dst = (bf16x4*)xb;  qbase = b * 1024; }
    else if (b < 2304) { src = (const float4*)W1; dst = (bf16x4*)W1b; qbase = (b - 2048) * 1024; }
    else if (b < 2308) { src = (const float4*)W2; dst = (bf16x4*)Wcb; qbase = (b - 2304) * 1024; }
    else               { src = (const float4*)W3; dst = (bf16x4*)(Wcb + NS * DM); qbase = (b - 2308) * 1024; }
    #pragma unroll
    for (int i = 0; i < 4; i++) {
        int q = qbase + i * 256 + t;
        float4 v = src[q];
        bf16x4 s;
        s.x = f2bf(v.x); s.y = f2bf(v.y); s.z = f2bf(v.z); s.w = f2bf(v.w);
        dst[q] = s;
    }
}

// ---------------------------------------------------------------------------
// Kernel 1: fused  z = xb @ W1b^T.  ROUND 4: 64x128 tile, grid (128 m, 8 n)
// = 1024 blocks = 4 blocks/CU = 4 waves/SIMD (2x round-3 latency hiding).
// XCD mapping FLIPPED: linear%8 = m-block%8, so each XCD's working set is
// xb-slice (2MB) + W1b (2MB) + Wc (64KB) ~= L2-resident (round 0-3 streamed
// all 16MB of xb through every XCD's 4MB L2 -> perpetual L2 misses that
// 2 waves/SIMD could not hide; 3 different staging schedules all ~83us).
// Fragments load directly global->VGPR (no barriers, no LDS in K-loop);
// per-lane base pointers + compile-time immediates. Numerics bit-identical
// to round 3 (same fragments, same MFMA accumulation order).
// Each wave: 64x32 output slice (acc[4][2]); bc MFMAs: wave w uses af[w]
// (wave-uniform branch, CONSTANT indices) covering m-rows w*16..w*16+15.
// ---------------------------------------------------------------------------
__global__ void __launch_bounds__(256, 4) gemm_fused(
    const short* __restrict__ xb, const short* __restrict__ W1b,
    const short* __restrict__ Wcb, const float* __restrict__ b1,
    const float* __restrict__ b2,  const float* __restrict__ b3,
    float* __restrict__ out)
{
    __shared__ float bcs[64];

    const int m0 = blockIdx.x * 64;     // grid.x = 128 m-blocks -> XCD = x%8
    const int n0 = blockIdx.y * 128;    // grid.y = 8 n-blocks
    const int t = threadIdx.x;
    const int lane = t & 63;
    const int w = t >> 6;               // 0..3
    const int wn = w * 32;              // wave's n-slice
    const int lm = lane & 15;
    const int quad = lane >> 4;

    // per-lane fragment base pointers (loop-invariant; K-loop adds only
    // compile-time byte immediates)
    const short* pA[4]; const short* pB[2]; const short* pW[2];
    #pragma unroll
    for (int i = 0; i < 4; i++)
        pA[i] = xb + (size_t)(m0 + i * 16 + lm) * DM + quad * 8;
    #pragma unroll
    for (int j = 0; j < 2; j++)
        pB[j] = W1b + (size_t)(n0 + wn + j * 16 + lm) * DM + quad * 8;
    #pragma unroll
    for (int h = 0; h < 2; h++)
        pW[h] = Wcb + (size_t)(h * 16 + lm) * DM + quad * 8;

    f32x4 acc[4][2] = {};    // main accumulators: [m-frag][n-frag]
    f32x4 abc[2]    = {};    // bc partials for af[w]: h=0:W2 h=1:W3

    #pragma unroll
    for (int kk = 0; kk < 16; kk++) {
        #pragma unroll
        for (int ks = 0; ks < 2; ks++) {
            const int eo = kk * 64 + ks * 32;   // element offset, compile-time
            bf16x8 af[4], bfv[2], wcv[2];
            #pragma unroll
            for (int i = 0; i < 4; i++)
                af[i] = *(const bf16x8*)(pA[i] + eo);
            #pragma unroll
            for (int j = 0; j < 2; j++)
                bfv[j] = *(const bf16x8*)(pB[j] + eo);
            #pragma unroll
            for (int h = 0; h < 2; h++)
                wcv[h] = *(const bf16x8*)(pW[h] + eo);

            #pragma unroll
            for (int i = 0; i < 4; i++)
                #pragma unroll
                for (int j = 0; j < 2; j++)
                    acc[i][j] = __builtin_amdgcn_mfma_f32_16x16x32_bf16(
                        af[i], bfv[j], acc[i][j], 0, 0, 0);

            // bc: wave w accumulates for m-frag w. WAVE-UNIFORM branch,
            // CONSTANT indices (dynamic af[w] would demote to scratch).
            if (w == 0) {
                abc[0] = __builtin_amdgcn_mfma_f32_16x16x32_bf16(af[0], wcv[0], abc[0], 0, 0, 0);
                abc[1] = __builtin_amdgcn_mfma_f32_16x16x32_bf16(af[0], wcv[1], abc[1], 0, 0, 0);
            } else if (w == 1) {
                abc[0] = __builtin_amdgcn_mfma_f32_16x16x32_bf16(af[1], wcv[0], abc[0], 0, 0, 0);
                abc[1] = __builtin_amdgcn_mfma_f32_16x16x32_bf16(af[1], wcv[1], abc[1], 0, 0, 0);
            } else if (w == 2) {
                abc[0] = __builtin_amdgcn_mfma_f32_16x16x32_bf16(af[2], wcv[0], abc[0], 0, 0, 0);
                abc[1] = __builtin_amdgcn_mfma_f32_16x16x32_bf16(af[2], wcv[1], abc[1], 0, 0, 0);
            } else {
                abc[0] = __builtin_amdgcn_mfma_f32_16x16x32_bf16(af[3], wcv[0], abc[0], 0, 0, 0);
                abc[1] = __builtin_amdgcn_mfma_f32_16x16x32_bf16(af[3], wcv[1], abc[1], 0, 0, 0);
            }
        }
    }

    // ---- bc reduce: lane holds rows w*16 + quad*4 + r, state col = lm ----
    float bb2 = b2[lm], bb3 = b3[lm];
    #pragma unroll
    for (int r = 0; r < 4; r++) {
        float p = (abc[0][r] + bb2) * (abc[1][r] + bb3);
        p += __shfl_xor(p, 1);
        p += __shfl_xor(p, 2);
        p += __shfl_xor(p, 4);
        p += __shfl_xor(p, 8);
        if (lm == 0) bcs[w * 16 + quad * 4 + r] = p;
    }
    __syncthreads();

    // ---- epilogue: D col(n)=lm, row(m)=quad*4+r; fast stable softplus ----
    const unsigned short* xbu = (const unsigned short*)xb;
    float b1v[2];
    #pragma unroll
    for (int j = 0; j < 2; j++) b1v[j] = b1[n0 + wn + j * 16 + lm];

    #pragma unroll
    for (int i = 0; i < 4; i++) {
        #pragma unroll
        for (int r = 0; r < 4; r++) {
            int lrow = i * 16 + quad * 4 + r;
            int gm = m0 + lrow;
            float bcv = bcs[lrow];
            const unsigned short* xrow = xbu + (size_t)gm * DM + n0 + wn + lm;
            float* orow = out + (size_t)gm * DM + n0 + wn + lm;
            #pragma unroll
            for (int j = 0; j < 2; j++) {
                float z = acc[i][j][r] + b1v[j];
                float az = __builtin_fabsf(z);
                float sp = fmaxf(z, 0.f) + __logf(1.f + __expf(-az));
                orow[j * 16] = bf2f(xrow[j * 16]) * sp * bcv;
            }
        }
    }
}

extern "C" void kernel_launch(void* const* d_in, const int* in_sizes, int n_in,
                              void* d_out, int out_size, void* d_ws, size_t ws_size,
                              hipStream_t stream) {
    const float* x  = (const float*)d_in[0];
    const float* W1 = (const float*)d_in[1];
    const float* b1 = (const float*)d_in[2];
    const float* W2 = (const float*)d_in[3];
    const float* b2 = (const float*)d_in[4];
    const float* W3 = (const float*)d_in[5];
    const float* b3 = (const float*)d_in[6];
    // d_in[7] = A is dead math
    float* out = (float*)d_out;

    // ws: xb 16 MiB @0 | W1b 2 MiB @16M | Wcb 64 KiB @18M
    char* ws = (char*)d_ws;
    short* xb  = (short*)(ws);
    short* W1b = (short*)(ws + (size_t)16 * 1024 * 1024);
    short* Wcb = (short*)(ws + (size_t)18 * 1024 * 1024);

    convert_all<<<2312, 256, 0, stream>>>(x, W1, W2, W3, xb, W1b, Wcb);

    // grid (128 m-blocks, 8 n-blocks): linear%8 = m-block%8 -> per-XCD
    // working set = xb slice (2MB) + W1b (2MB) + Wc (64KB) ~ L2-resident
    dim3 grid(M_ROWS / 64, DM / 128);
    gemm_fused<<<grid, 256, 0, stream>>>(xb, W1b, Wcb, b1, b2, b3, out);
}

// Round 5
// 128.138 us; speedup vs baseline: 1.6670x; 1.6670x over previous
//
#include <hip/hip_runtime.h>
#include <hip/hip_bf16.h>
#include <cmath>

#define BATCH 4
#define SEQ 2048
#define DM 1024
#define NS 16
#define M_ROWS (BATCH * SEQ)

typedef short bf16x8 __attribute__((ext_vector_type(8)));
typedef short bf16x4 __attribute__((ext_vector_type(4)));
typedef float f32x4 __attribute__((ext_vector_type(4)));

// fp32 -> bf16 round-to-nearest-even
__device__ __forceinline__ short f2bf(float f) {
    union { float f; unsigned u; } a; a.f = f;
    unsigned u = a.u;
    return (short)((u + 0x7fffu + ((u >> 16) & 1u)) >> 16);
}
__device__ __forceinline__ float bf2f(unsigned short s) {
    union { unsigned u; float f; } a; a.u = ((unsigned)s) << 16;
    return a.f;
}

#define LDS_CAST(p) ((__attribute__((address_space(3))) unsigned*)(p))
#define GLB_CAST(p) ((const __attribute__((address_space(1))) unsigned*)(p))

// ---------------------------------------------------------------------------
// Kernel 0: convert x, W1, W2, W3 fp32 -> bf16. Block-uniform segment select.
// Wcb = [W2(16 rows); W3(16 rows)], row-major, K contiguous.
// ---------------------------------------------------------------------------
__global__ void __launch_bounds__(256) convert_all(
    const float* __restrict__ x,  const float* __restrict__ W1,
    const float* __restrict__ W2, const float* __restrict__ W3,
    short* __restrict__ xb, short* __restrict__ W1b, short* __restrict__ Wcb)
{
    const int b = blockIdx.x;
    const int t = threadIdx.x;
    const float4* src; bf16x4* dst; int qbase;
    if (b < 2048)      { src = (const float4*)x;  dst = (bf16x4*)xb;  qbase = b * 1024; }
    else if (b < 2304) { src = (const float4*)W1; dst = (bf16x4*)W1b; qbase = (b - 2048) * 1024; }
    else if (b < 2308) { src = (const float4*)W2; dst = (bf16x4*)Wcb; qbase = (b - 2304) * 1024; }
    else               { src = (const float4*)W3; dst = (bf16x4*)(Wcb + NS * DM); qbase = (b - 2308) * 1024; }
    #pragma unroll
    for (int i = 0; i < 4; i++) {
        int q = qbase + i * 256 + t;
        float4 v = src[q];
        bf16x4 s;
        s.x = f2bf(v.x); s.y = f2bf(v.y); s.z = f2bf(v.z); s.w = f2bf(v.w);
        dst[q] = s;
    }
}

// ---------------------------------------------------------------------------
// Kernel 1: fused  z = xb @ W1b^T.  ROUND 5: R0's LDS-staged 2-barrier
// structure (best measured: 81us) with the ONE never-isolated variable
// changed: tile 128x128 -> 64x128, grid 512 -> 1024 blocks = 4 blocks/CU
// (16 waves/CU).  Unified model of rounds 0-4: every version is bound by
// per-CU outstanding line-fill parallelism (~0.2 lines/cyc/CU effective,
// nothing saturated); R0's barrier drain was never the cost -- there was
// just nothing co-resident to run during it.  4 independent blocks/CU let
// cross-block overlap cover each block's drain.  XCD mapping = R0's
// (grid.x = n-block -> per-XCD W1b slice 256KB L2-resident, xb streams via
// L3; avoids R4's 4MB L2 thrash).  Waves split N (acc[4][2]); bc via
// wave-uniform af[w] (R4 scheme, verified).  LDS 28.25KB.
// ---------------------------------------------------------------------------
__global__ void __launch_bounds__(256, 4) gemm_fused(
    const short* __restrict__ xb, const short* __restrict__ W1b,
    const short* __restrict__ Wcb, const float* __restrict__ b1,
    const float* __restrict__ b2,  const float* __restrict__ b3,
    float* __restrict__ out)
{
    __shared__ short As[64][64];     //  8 KB  x tile   [m][k]
    __shared__ short Bs[128][64];    // 16 KB  W1 tile  [n][k]
    __shared__ short Wcs[32][64];    //  4 KB  Wc tile  [n][k]
    __shared__ float bcs[64];

    const int n0 = blockIdx.x * 128;    // grid.x = 8 n-blocks -> XCD = x
    const int m0 = blockIdx.y * 64;     // grid.y = 128 m-blocks
    const int t = threadIdx.x;
    const int lane = t & 63;
    const int w = t >> 6;               // 0..3
    const int wn = w * 32;              // wave's n-slice
    const int lm = lane & 15;
    const int quad = lane >> 4;

    // staging: 8 chunks of 16B per 64-element row; 32-row groups
    const int sr  = t >> 3;               // 0..31
    const int sc  = t & 7;                // 0..7
    const int gch = (sc ^ (sr & 7)) * 8;  // swizzled k-element offset

    // loop-invariant staging pointers
    const short* pa = xb  + (size_t)(m0 + sr) * DM + gch;
    const short* pb = W1b + (size_t)(n0 + sr) * DM + gch;
    const short* pw = Wcb + (size_t)sr        * DM + gch;

    f32x4 acc[4][2] = {};    // main accumulators: [m-frag][n-frag]
    f32x4 abc[2]    = {};    // bc partials for af[w]: h=0:W2 h=1:W3

    #pragma unroll
    for (int kk = 0; kk < 16; kk++) {
        const int ke = kk * 64;          // element offset, constant per iter
        // A: 64 rows in 2 groups of 32
        #pragma unroll
        for (int u = 0; u < 2; u++)
            __builtin_amdgcn_global_load_lds(GLB_CAST(pa + (size_t)(u * 32) * DM + ke),
                LDS_CAST(&As[u * 32 + sr][sc * 8]), 16, 0, 0);
        // B: 128 rows in 4 groups of 32
        #pragma unroll
        for (int u = 0; u < 4; u++)
            __builtin_amdgcn_global_load_lds(GLB_CAST(pb + (size_t)(u * 32) * DM + ke),
                LDS_CAST(&Bs[u * 32 + sr][sc * 8]), 16, 0, 0);
        // Wc: 32 rows
        __builtin_amdgcn_global_load_lds(GLB_CAST(pw + ke),
            LDS_CAST(&Wcs[sr][sc * 8]), 16, 0, 0);
        __syncthreads();

        #pragma unroll
        for (int ks = 0; ks < 2; ks++) {
            // all fragment rows have (row&7) == (lm&7) -> shared chunk index
            const int cs = ((ks * 4 + quad) ^ (lm & 7)) * 8;
            bf16x8 af[4], bfv[2], wcv[2];
            #pragma unroll
            for (int i = 0; i < 4; i++)
                af[i] = *(const bf16x8*)&As[i * 16 + lm][cs];
            #pragma unroll
            for (int j = 0; j < 2; j++)
                bfv[j] = *(const bf16x8*)&Bs[wn + j * 16 + lm][cs];
            #pragma unroll
            for (int h = 0; h < 2; h++)
                wcv[h] = *(const bf16x8*)&Wcs[h * 16 + lm][cs];

            #pragma unroll
            for (int i = 0; i < 4; i++)
                #pragma unroll
                for (int j = 0; j < 2; j++)
                    acc[i][j] = __builtin_amdgcn_mfma_f32_16x16x32_bf16(
                        af[i], bfv[j], acc[i][j], 0, 0, 0);

            // bc: wave w accumulates for m-frag w. WAVE-UNIFORM branch,
            // CONSTANT indices (dynamic af[w] would demote to scratch).
            if (w == 0) {
                abc[0] = __builtin_amdgcn_mfma_f32_16x16x32_bf16(af[0], wcv[0], abc[0], 0, 0, 0);
                abc[1] = __builtin_amdgcn_mfma_f32_16x16x32_bf16(af[0], wcv[1], abc[1], 0, 0, 0);
            } else if (w == 1) {
                abc[0] = __builtin_amdgcn_mfma_f32_16x16x32_bf16(af[1], wcv[0], abc[0], 0, 0, 0);
                abc[1] = __builtin_amdgcn_mfma_f32_16x16x32_bf16(af[1], wcv[1], abc[1], 0, 0, 0);
            } else if (w == 2) {
                abc[0] = __builtin_amdgcn_mfma_f32_16x16x32_bf16(af[2], wcv[0], abc[0], 0, 0, 0);
                abc[1] = __builtin_amdgcn_mfma_f32_16x16x32_bf16(af[2], wcv[1], abc[1], 0, 0, 0);
            } else {
                abc[0] = __builtin_amdgcn_mfma_f32_16x16x32_bf16(af[3], wcv[0], abc[0], 0, 0, 0);
                abc[1] = __builtin_amdgcn_mfma_f32_16x16x32_bf16(af[3], wcv[1], abc[1], 0, 0, 0);
            }
        }
        __syncthreads();
    }

    // ---- bc reduce: lane holds rows w*16 + quad*4 + r, state col = lm ----
    float bb2 = b2[lm], bb3 = b3[lm];
    #pragma unroll
    for (int r = 0; r < 4; r++) {
        float p = (abc[0][r] + bb2) * (abc[1][r] + bb3);
        p += __shfl_xor(p, 1);
        p += __shfl_xor(p, 2);
        p += __shfl_xor(p, 4);
        p += __shfl_xor(p, 8);
        if (lm == 0) bcs[w * 16 + quad * 4 + r] = p;
    }
    __syncthreads();

    // ---- epilogue: D col(n)=lm, row(m)=quad*4+r; fast stable softplus ----
    const unsigned short* xbu = (const unsigned short*)xb;
    float b1v[2];
    #pragma unroll
    for (int j = 0; j < 2; j++) b1v[j] = b1[n0 + wn + j * 16 + lm];

    #pragma unroll
    for (int i = 0; i < 4; i++) {
        #pragma unroll
        for (int r = 0; r < 4; r++) {
            int lrow = i * 16 + quad * 4 + r;
            int gm = m0 + lrow;
            float bcv = bcs[lrow];
            const unsigned short* xrow = xbu + (size_t)gm * DM + n0 + wn + lm;
            float* orow = out + (size_t)gm * DM + n0 + wn + lm;
            #pragma unroll
            for (int j = 0; j < 2; j++) {
                float z = acc[i][j][r] + b1v[j];
                float az = __builtin_fabsf(z);
                float sp = fmaxf(z, 0.f) + __logf(1.f + __expf(-az));
                orow[j * 16] = bf2f(xrow[j * 16]) * sp * bcv;
            }
        }
    }
}

extern "C" void kernel_launch(void* const* d_in, const int* in_sizes, int n_in,
                              void* d_out, int out_size, void* d_ws, size_t ws_size,
                              hipStream_t stream) {
    const float* x  = (const float*)d_in[0];
    const float* W1 = (const float*)d_in[1];
    const float* b1 = (const float*)d_in[2];
    const float* W2 = (const float*)d_in[3];
    const float* b2 = (const float*)d_in[4];
    const float* W3 = (const float*)d_in[5];
    const float* b3 = (const float*)d_in[6];
    // d_in[7] = A is dead math
    float* out = (float*)d_out;

    // ws: xb 16 MiB @0 | W1b 2 MiB @16M | Wcb 64 KiB @18M
    char* ws = (char*)d_ws;
    short* xb  = (short*)(ws);
    short* W1b = (short*)(ws + (size_t)16 * 1024 * 1024);
    short* Wcb = (short*)(ws + (size_t)18 * 1024 * 1024);

    convert_all<<<2312, 256, 0, stream>>>(x, W1, W2, W3, xb, W1b, Wcb);

    // grid (8 n-blocks, 128 m-blocks): linear%8 = n-block = XCD ->
    // per-XCD W1b slice (256KB) L2-resident, xb streams via L3.
    // 1024 blocks = 4 blocks/CU = 16 waves/CU.
    dim3 grid(DM / 128, M_ROWS / 64);
    gemm_fused<<<grid, 256, 0, stream>>>(xb, W1b, Wcb, b1, b2, b3, out);
}